// Round 5
// baseline (4695.193 us; speedup 1.0000x reference)
//
#include <hip/hip_runtime.h>
#include <cstdint>
#include <cstddef>

// Problem constants (fixed by the reference).
#define B_   2048
#define T_   100
#define U_   512
#define NG_  2048   // 4*U
#define C_   10

typedef __attribute__((ext_vector_type(8))) short   short8;
typedef __attribute__((ext_vector_type(4))) float   floatx4;
typedef unsigned short ushort_t;

__device__ inline ushort_t f2bf(float f){
  unsigned u = __float_as_uint(f);
  unsigned r = (u + 0x7FFFu + ((u >> 16) & 1u)) >> 16;   // RNE
  return (ushort_t)r;
}
__device__ inline float bf2f(ushort_t b){ return __uint_as_float(((unsigned)b) << 16); }

__device__ inline float sigm(float x){ return 1.0f / (1.0f + __expf(-x)); }
__device__ inline float tanh_fast(float x){
  float a = fabsf(x);
  float e = __expf(-2.0f * a);          // no overflow: e in (0,1]
  float r = (1.0f - e) / (1.0f + e);
  return copysignf(r, x);
}

// Column permutation: permuted col p -> original gate-major col.
// Tile T (128 cols) owns u in [T*32, T*32+32); within tile: two 64-col halves,
// each half = 4 gates x 16 u's, gate-major in 16-col groups.
__device__ inline int orig_col(int p){
  int Tt  = p >> 7;
  int loc = p & 127;
  int half = loc >> 6;
  int loc2 = loc & 63;
  int gate = loc2 >> 4;
  int uu   = (half << 4) | (loc2 & 15);
  return gate * U_ + Tt * 32 + uu;
}

#define AS1(p) ((const __attribute__((address_space(1))) void*)(p))
#define AS3(p) ((__attribute__((address_space(3))) void*)(p))

// ---------------------------------------------------------------------------
// One-time (per launch) weight repack: fp32 -> bf16, B^T (n-major) layout with
// gate-interleaved column permutation. Also permuted biases (fp32) and W0 row.
// ---------------------------------------------------------------------------
__global__ void convert_weights(
    const float* __restrict__ W0, const float* __restrict__ U0, const float* __restrict__ b0,
    const float* __restrict__ W1, const float* __restrict__ U1, const float* __restrict__ b1,
    const float* __restrict__ W2, const float* __restrict__ U2, const float* __restrict__ b2,
    ushort_t* __restrict__ Bt0, ushort_t* __restrict__ Bt1, ushort_t* __restrict__ Bt2,
    float* __restrict__ W0p, float* __restrict__ biasp)
{
  const int N0 = NG_ * 512;     // Bt0 elements
  const int N1 = NG_ * 1024;    // Bt1/Bt2 elements
  const int total = N0 + 2 * N1 + NG_ + 3 * NG_;
  int idx = blockIdx.x * 256 + threadIdx.x;
  if (idx >= total) return;

  if (idx < N0){
    int p = idx >> 9, k = idx & 511;
    Bt0[idx] = f2bf(U0[(size_t)k * NG_ + orig_col(p)]);
  } else if (idx < N0 + N1){
    int j = idx - N0; int p = j >> 10, k = j & 1023;
    int oc = orig_col(p);
    float v = (k < 512) ? W1[(size_t)k * NG_ + oc] : U1[(size_t)(k - 512) * NG_ + oc];
    Bt1[j] = f2bf(v);
  } else if (idx < N0 + 2 * N1){
    int j = idx - N0 - N1; int p = j >> 10, k = j & 1023;
    int oc = orig_col(p);
    float v = (k < 512) ? W2[(size_t)k * NG_ + oc] : U2[(size_t)(k - 512) * NG_ + oc];
    Bt2[j] = f2bf(v);
  } else if (idx < N0 + 2 * N1 + NG_){
    int p = idx - N0 - 2 * N1;
    W0p[p] = W0[orig_col(p)];
  } else {
    int j = idx - N0 - 2 * N1 - NG_;
    int l = j >> 11, p = j & 2047;
    const float* bs = (l == 0) ? b0 : (l == 1) ? b1 : b2;
    biasp[j] = bs[orig_col(p)];
  }
}

// ---------------------------------------------------------------------------
// LIGHT task (layer 0, K=512): 128x128 tile, 2x2 waves, 4x4 frags. BK=64,
// bank-conflict-killing slot rotation (slot (r,j) holds chunk (j+r)&7).
// ---------------------------------------------------------------------------
__device__ __forceinline__ void do_task_l0(
    const ushort_t* __restrict__ A0,   // h_prev layer 0
    const ushort_t* __restrict__ Bt,   // (2048 x 512) bf16, n-major permuted
    const float* __restrict__ biasp,
    const float* __restrict__ W0p,
    const float* __restrict__ x,
    const int* __restrict__ mask,
    float* __restrict__ cbuf,
    const ushort_t* __restrict__ hprev,
    ushort_t* __restrict__ hout,
    int t, int mt, int nt,
    ushort_t* tA, ushort_t* tB)
{
  const int tid  = threadIdx.x;
  const int wv   = tid >> 6;
  const int lane = tid & 63;
  const int qd   = lane >> 4;
  const int l16  = lane & 15;
  const int wave_m = wv >> 1;
  const int wave_n = wv & 1;
  const int m0 = mt * 128, n0 = nt * 128;

  int srow[4], scol[4];
  #pragma unroll
  for (int g = 0; g < 4; ++g){
    int i = g * 256 + tid;
    srow[g] = i >> 3;
    scol[g] = ((i & 7) + (i >> 3)) & 7;
  }

  int aoff[2][4], boff[2][4];
  #pragma unroll
  for (int ks = 0; ks < 2; ++ks){
    #pragma unroll
    for (int w = 0; w < 4; ++w){
      int Ra = wave_m * 64 + w * 16 + l16;
      int Rb = wave_n * 64 + w * 16 + l16;
      int q  = ks * 4 + qd;
      aoff[ks][w] = Ra * 64 + ((q - Ra) & 7) * 8;
      boff[ks][w] = Rb * 64 + ((q - Rb) & 7) * 8;
    }
  }

  floatx4 acc[4][4];
  #pragma unroll
  for (int i = 0; i < 4; ++i)
    #pragma unroll
    for (int j = 0; j < 4; ++j) acc[i][j] = (floatx4){0.f, 0.f, 0.f, 0.f};

  for (int k0 = 0; k0 < 512; k0 += 64){
    #pragma unroll
    for (int g = 0; g < 4; ++g){
      int ibase = g * 256 + wv * 64;
      const ushort_t* ga = A0 + (size_t)(m0 + srow[g]) * U_ + k0 + scol[g] * 8;
      __builtin_amdgcn_global_load_lds(AS1(ga), AS3(&tA[ibase * 8]), 16, 0, 0);
      const ushort_t* gb = Bt + (size_t)(n0 + srow[g]) * 512 + k0 + scol[g] * 8;
      __builtin_amdgcn_global_load_lds(AS1(gb), AS3(&tB[ibase * 8]), 16, 0, 0);
    }
    __syncthreads();

    #pragma unroll
    for (int ks = 0; ks < 2; ++ks){
      short8 af[4], bfr[4];
      #pragma unroll
      for (int wm = 0; wm < 4; ++wm) af[wm] = *(const short8*)&tA[aoff[ks][wm]];
      #pragma unroll
      for (int wn = 0; wn < 4; ++wn) bfr[wn] = *(const short8*)&tB[boff[ks][wn]];
      #pragma unroll
      for (int wm = 0; wm < 4; ++wm)
        #pragma unroll
        for (int wn = 0; wn < 4; ++wn)
          acc[wm][wn] = __builtin_amdgcn_mfma_f32_16x16x32_bf16(af[wm], bfr[wn], acc[wm][wn], 0, 0, 0);
    }
    __syncthreads();
  }

  const int u  = nt * 32 + wave_n * 16 + l16;
  const int pb = nt * 128 + wave_n * 64 + l16;
  const float bi = biasp[pb], bf_ = biasp[pb + 16], bg = biasp[pb + 32], bo = biasp[pb + 48];
  const float wi = W0p[pb], wf = W0p[pb + 16], wg = W0p[pb + 32], wo = W0p[pb + 48];

  #pragma unroll
  for (int wm = 0; wm < 4; ++wm){
    #pragma unroll
    for (int reg = 0; reg < 4; ++reg){
      int b = m0 + wave_m * 64 + wm * 16 + qd * 4 + reg;
      float xv = x[(size_t)b * T_ + t];
      int mk = mask[(size_t)b * T_ + t];
      float zi = acc[wm][0][reg] + bi + xv * wi;
      float zf = acc[wm][1][reg] + bf_ + xv * wf;
      float zg = acc[wm][2][reg] + bg + xv * wg;
      float zo = acc[wm][3][reg] + bo + xv * wo;
      size_t su = (size_t)b * U_ + u;
      float c_old = cbuf[su];
      float i_ = sigm(zi), f_ = sigm(zf), g_ = tanh_fast(zg), o_ = sigm(zo);
      float c_new = f_ * c_old + i_ * g_;
      float h_new = o_ * tanh_fast(c_new);
      ushort_t hb = mk ? f2bf(h_new) : hprev[su];
      cbuf[su] = mk ? c_new : c_old;
      hout[su] = hb;
    }
  }
}

// ---------------------------------------------------------------------------
// WIDE task (layers 1/2, K=1024): 128x256 tile, 2x2 waves, each wave 4x8
// frags (~128 acc VGPRs). Halves A-staging traffic and per-CU drain count.
// ---------------------------------------------------------------------------
__device__ __forceinline__ void do_task_wide(
    const ushort_t* __restrict__ A0,   // h_below (phase 0)
    const ushort_t* __restrict__ A1,   // h_prev  (phase 1)
    const ushort_t* __restrict__ Bt,   // (2048 x 1024) bf16, n-major permuted
    const float* __restrict__ biasp,
    const int* __restrict__ mask,
    float* __restrict__ cbuf,
    const ushort_t* __restrict__ hprev,
    ushort_t* __restrict__ hout,
    int t, int mt, int nt2,
    ushort_t* tA, ushort_t* tB)
{
  const int tid  = threadIdx.x;
  const int wv   = tid >> 6;
  const int lane = tid & 63;
  const int qd   = lane >> 4;
  const int l16  = lane & 15;
  const int wave_m = wv >> 1;
  const int wave_n = wv & 1;
  const int m0 = mt * 128, n0 = nt2 * 256;

  int srA[4], scA[4], srB[8], scB[8];
  #pragma unroll
  for (int g = 0; g < 4; ++g){
    int i = g * 256 + tid;
    srA[g] = i >> 3; scA[g] = ((i & 7) + (i >> 3)) & 7;
  }
  #pragma unroll
  for (int g = 0; g < 8; ++g){
    int i = g * 256 + tid;
    srB[g] = i >> 3; scB[g] = ((i & 7) + (i >> 3)) & 7;
  }

  int aoff[2][4], boff[2][8];
  #pragma unroll
  for (int ks = 0; ks < 2; ++ks){
    int q = ks * 4 + qd;
    #pragma unroll
    for (int w = 0; w < 4; ++w){
      int Ra = wave_m * 64 + w * 16 + l16;
      aoff[ks][w] = Ra * 64 + ((q - Ra) & 7) * 8;
    }
    #pragma unroll
    for (int w = 0; w < 8; ++w){
      int Rb = wave_n * 128 + w * 16 + l16;
      boff[ks][w] = Rb * 64 + ((q - Rb) & 7) * 8;
    }
  }

  floatx4 acc[4][8];
  #pragma unroll
  for (int i = 0; i < 4; ++i)
    #pragma unroll
    for (int j = 0; j < 8; ++j) acc[i][j] = (floatx4){0.f, 0.f, 0.f, 0.f};

  #pragma unroll 1
  for (int ph = 0; ph < 2; ++ph){
    const ushort_t* A = ph ? A1 : A0;
    for (int k0 = 0; k0 < 512; k0 += 64){
      #pragma unroll
      for (int g = 0; g < 4; ++g){
        int ibase = g * 256 + wv * 64;
        const ushort_t* ga = A + (size_t)(m0 + srA[g]) * U_ + k0 + scA[g] * 8;
        __builtin_amdgcn_global_load_lds(AS1(ga), AS3(&tA[ibase * 8]), 16, 0, 0);
      }
      #pragma unroll
      for (int g = 0; g < 8; ++g){
        int ibase = g * 256 + wv * 64;
        const ushort_t* gb = Bt + (size_t)(n0 + srB[g]) * 1024 + ph * 512 + k0 + scB[g] * 8;
        __builtin_amdgcn_global_load_lds(AS1(gb), AS3(&tB[ibase * 8]), 16, 0, 0);
      }
      __syncthreads();

      #pragma unroll
      for (int ks = 0; ks < 2; ++ks){
        short8 af[4], bfr[8];
        #pragma unroll
        for (int wm = 0; wm < 4; ++wm) af[wm] = *(const short8*)&tA[aoff[ks][wm]];
        #pragma unroll
        for (int wn = 0; wn < 8; ++wn) bfr[wn] = *(const short8*)&tB[boff[ks][wn]];
        #pragma unroll
        for (int wm = 0; wm < 4; ++wm)
          #pragma unroll
          for (int wn = 0; wn < 8; ++wn)
            acc[wm][wn] = __builtin_amdgcn_mfma_f32_16x16x32_bf16(af[wm], bfr[wn], acc[wm][wn], 0, 0, 0);
      }
      __syncthreads();
    }
  }

  // ---- epilogue: wave covers permuted tile ntp = nt2*2 + wave_n; per lane
  // two u's (halves h2=0,1), frag wn = h2*4 + gate.
  const int ntp = nt2 * 2 + wave_n;
  float bb[2][4];
  #pragma unroll
  for (int h2 = 0; h2 < 2; ++h2){
    int pb = ntp * 128 + h2 * 64 + l16;
    #pragma unroll
    for (int g = 0; g < 4; ++g) bb[h2][g] = biasp[pb + g * 16];
  }

  #pragma unroll
  for (int wm = 0; wm < 4; ++wm){
    #pragma unroll
    for (int reg = 0; reg < 4; ++reg){
      int b = m0 + wave_m * 64 + wm * 16 + qd * 4 + reg;
      int mk = mask[(size_t)b * T_ + t];
      #pragma unroll
      for (int h2 = 0; h2 < 2; ++h2){
        int u = ntp * 32 + h2 * 16 + l16;
        float zi = acc[wm][h2 * 4 + 0][reg] + bb[h2][0];
        float zf = acc[wm][h2 * 4 + 1][reg] + bb[h2][1];
        float zg = acc[wm][h2 * 4 + 2][reg] + bb[h2][2];
        float zo = acc[wm][h2 * 4 + 3][reg] + bb[h2][3];
        size_t su = (size_t)b * U_ + u;
        float c_old = cbuf[su];
        float i_ = sigm(zi), f_ = sigm(zf), g_ = tanh_fast(zg), o_ = sigm(zo);
        float c_new = f_ * c_old + i_ * g_;
        float h_new = o_ * tanh_fast(c_new);
        ushort_t hbv = mk ? f2bf(h_new) : hprev[su];
        cbuf[su] = mk ? c_new : c_old;
        hout[su] = hbv;
      }
    }
  }
}

// ---------------------------------------------------------------------------
// One wavefront phase. Grid = 512 blocks = exactly 2/CU:
//   lin   0..127 : L1 wide tiles (16 mt x 8 nt2)  — launched first
//   lin 128..255 : L2 wide tiles
//   lin 256..511 : L0 light tiles (16 mt x 16 nt)
// Wide-first ordering pairs 1 wide + 1 light per CU under round-robin
// dispatch; lin%8 keeps each task's B-slice on one XCD (L2-hot).
// ---------------------------------------------------------------------------
__global__ __launch_bounds__(256, 2) void lstm_phase(
    const ushort_t* __restrict__ Bt0, const ushort_t* __restrict__ Bt1,
    const ushort_t* __restrict__ Bt2, const float* __restrict__ biasp,
    const float* __restrict__ W0p, const float* __restrict__ x,
    const int* __restrict__ mask,
    ushort_t* h00, ushort_t* h01, ushort_t* h10, ushort_t* h11,
    ushort_t* h20, ushort_t* h21,
    float* c0, float* c1, float* c2,
    int s)
{
  __shared__ __align__(16) ushort_t tA[128 * 64];
  __shared__ __align__(16) ushort_t tB[256 * 64];

  const int lin = blockIdx.x;

  ushort_t* h0[2] = {h00, h01};
  ushort_t* h1[2] = {h10, h11};
  ushort_t* h2[2] = {h20, h21};

  if (lin < 128){
    if (s < 1 || s > 100) return;
    int t = s - 1, p = t & 1;
    do_task_wide(h0[p ^ 1], h1[p], Bt1, biasp + NG_, mask,
                 c1, h1[p], h1[p ^ 1], t, lin >> 3, lin & 7, tA, tB);
  } else if (lin < 256){
    if (s < 2) return;
    int j = lin - 128, t = s - 2, p = t & 1;
    do_task_wide(h1[p ^ 1], h2[p], Bt2, biasp + 2 * NG_, mask,
                 c2, h2[p], h2[p ^ 1], t, j >> 3, j & 7, tA, tB);
  } else {
    if (s >= 100) return;
    int tile = lin - 256, t = s, p = t & 1;
    do_task_l0(h0[p], Bt0, biasp, W0p, x, mask,
               c0, h0[p], h0[p ^ 1], t, tile >> 4, tile & 15, tA, tB);
  }
}

// ---------------------------------------------------------------------------
// Head: logits = h2 @ Wd + bd, softmax. One wave per batch row.
// ---------------------------------------------------------------------------
__global__ __launch_bounds__(256) void head_softmax(
    const ushort_t* __restrict__ h2, const float* __restrict__ Wd,
    const float* __restrict__ bd, float* __restrict__ out)
{
  int wv = threadIdx.x >> 6, lane = threadIdx.x & 63;
  int row = blockIdx.x * 4 + wv;
  const ushort_t* hr = h2 + (size_t)row * U_;

  float acc[C_];
  #pragma unroll
  for (int c = 0; c < C_; ++c) acc[c] = 0.f;

  short8 hv = *(const short8*)&hr[lane * 8];
  #pragma unroll
  for (int j = 0; j < 8; ++j){
    float hf = bf2f((ushort_t)hv[j]);
    int k = lane * 8 + j;
    #pragma unroll
    for (int c = 0; c < C_; ++c) acc[c] += hf * Wd[k * C_ + c];
  }
  #pragma unroll
  for (int c = 0; c < C_; ++c){
    float v = acc[c];
    #pragma unroll
    for (int off = 32; off > 0; off >>= 1) v += __shfl_xor(v, off);
    acc[c] = v + bd[c];
  }
  float mx = acc[0];
  #pragma unroll
  for (int c = 1; c < C_; ++c) mx = fmaxf(mx, acc[c]);
  float e[C_]; float s = 0.f;
  #pragma unroll
  for (int c = 0; c < C_; ++c){ e[c] = __expf(acc[c] - mx); s += e[c]; }
  float inv = 1.0f / s;
  if (lane == 0){
    #pragma unroll
    for (int c = 0; c < C_; ++c) out[(size_t)row * C_ + c] = e[c] * inv;
  }
}

// ---------------------------------------------------------------------------
extern "C" void kernel_launch(void* const* d_in, const int* in_sizes, int n_in,
                              void* d_out, int out_size, void* d_ws, size_t ws_size,
                              hipStream_t stream)
{
  const float* x  = (const float*)d_in[0];
  const int*  mask= (const int*)  d_in[1];
  const float* W0 = (const float*)d_in[2];
  const float* U0 = (const float*)d_in[3];
  const float* b0 = (const float*)d_in[4];
  const float* W1 = (const float*)d_in[5];
  const float* U1 = (const float*)d_in[6];
  const float* b1 = (const float*)d_in[7];
  const float* W2 = (const float*)d_in[8];
  const float* U2 = (const float*)d_in[9];
  const float* b2 = (const float*)d_in[10];
  const float* Wd = (const float*)d_in[11];
  const float* bd = (const float*)d_in[12];
  float* out = (float*)d_out;

  char* ws = (char*)d_ws;
  size_t off = 0;
  auto alloc = [&](size_t sz) -> char* {
    char* p = ws + off; off = (off + sz + 255) & ~(size_t)255; return p;
  };
  ushort_t* Bt0  = (ushort_t*)alloc((size_t)NG_ * 512 * 2);
  ushort_t* Bt1  = (ushort_t*)alloc((size_t)NG_ * 1024 * 2);
  ushort_t* Bt2  = (ushort_t*)alloc((size_t)NG_ * 1024 * 2);
  float*    W0p  = (float*)alloc((size_t)NG_ * 4);
  float*    biasp= (float*)alloc((size_t)3 * NG_ * 4);

  // State: h[3][2] (bf16) + c[3] (fp32), one contiguous memset region.
  const size_t hsz = (size_t)B_ * U_ * 2;
  const size_t csz = (size_t)B_ * U_ * 4;
  char* state = alloc(6 * hsz + 3 * csz);
  ushort_t* hb[3][2]; float* cb[3];
  {
    char* pp = state;
    for (int l = 0; l < 3; ++l)
      for (int par = 0; par < 2; ++par){ hb[l][par] = (ushort_t*)pp; pp += hsz; }
    for (int l = 0; l < 3; ++l){ cb[l] = (float*)pp; pp += csz; }
  }

  hipMemsetAsync(state, 0, 6 * hsz + 3 * csz, stream);

  const int total = NG_ * 512 + 2 * NG_ * 1024 + NG_ + 3 * NG_;
  convert_weights<<<(total + 255) / 256, 256, 0, stream>>>(
      W0, U0, b0, W1, U1, b1, W2, U2, b2, Bt0, Bt1, Bt2, W0p, biasp);

  for (int s = 0; s < 102; ++s){
    lstm_phase<<<512, 256, 0, stream>>>(
        Bt0, Bt1, Bt2, biasp, W0p, x, mask,
        hb[0][0], hb[0][1], hb[1][0], hb[1][1], hb[2][0], hb[2][1],
        cb[0], cb[1], cb[2], s);
  }

  // T=100: layer-2 final h (t=99) lands in parity-0 buffer.
  head_softmax<<<B_ / 4, 256, 0, stream>>>(hb[2][0], Wd, bd, out);
}

// Round 6
// 4408.807 us; speedup vs baseline: 1.0650x; 1.0650x over previous
//
#include <hip/hip_runtime.h>
#include <cstdint>
#include <cstddef>

// Problem constants (fixed by the reference).
#define B_   2048
#define T_   100
#define U_   512
#define NG_  2048   // 4*U
#define C_   10

typedef __attribute__((ext_vector_type(8))) short   short8;
typedef __attribute__((ext_vector_type(4))) float   floatx4;
typedef unsigned short ushort_t;

__device__ inline ushort_t f2bf(float f){
  unsigned u = __float_as_uint(f);
  unsigned r = (u + 0x7FFFu + ((u >> 16) & 1u)) >> 16;   // RNE
  return (ushort_t)r;
}
__device__ inline float bf2f(ushort_t b){ return __uint_as_float(((unsigned)b) << 16); }

__device__ inline float sigm(float x){ return 1.0f / (1.0f + __expf(-x)); }
__device__ inline float tanh_fast(float x){
  float a = fabsf(x);
  float e = __expf(-2.0f * a);          // no overflow: e in (0,1]
  float r = (1.0f - e) / (1.0f + e);
  return copysignf(r, x);
}

// Column permutation: permuted col p -> original gate-major col.
// Tile T (128 cols) owns u in [T*32, T*32+32); within tile: two 64-col halves,
// each half = 4 gates x 16 u's, gate-major in 16-col groups.
__device__ inline int orig_col(int p){
  int Tt  = p >> 7;
  int loc = p & 127;
  int half = loc >> 6;
  int loc2 = loc & 63;
  int gate = loc2 >> 4;
  int uu   = (half << 4) | (loc2 & 15);
  return gate * U_ + Tt * 32 + uu;
}

#define AS1(p) ((const __attribute__((address_space(1))) void*)(p))
#define AS3(p) ((__attribute__((address_space(3))) void*)(p))

// ---------------------------------------------------------------------------
// One-time (per launch) weight repack: fp32 -> bf16, B^T (n-major) layout with
// gate-interleaved column permutation. Also permuted biases (fp32) and W0 row.
// ---------------------------------------------------------------------------
__global__ void convert_weights(
    const float* __restrict__ W0, const float* __restrict__ U0, const float* __restrict__ b0,
    const float* __restrict__ W1, const float* __restrict__ U1, const float* __restrict__ b1,
    const float* __restrict__ W2, const float* __restrict__ U2, const float* __restrict__ b2,
    ushort_t* __restrict__ Bt0, ushort_t* __restrict__ Bt1, ushort_t* __restrict__ Bt2,
    float* __restrict__ W0p, float* __restrict__ biasp)
{
  const int N0 = NG_ * 512;     // Bt0 elements
  const int N1 = NG_ * 1024;    // Bt1/Bt2 elements
  const int total = N0 + 2 * N1 + NG_ + 3 * NG_;
  int idx = blockIdx.x * 256 + threadIdx.x;
  if (idx >= total) return;

  if (idx < N0){
    int p = idx >> 9, k = idx & 511;
    Bt0[idx] = f2bf(U0[(size_t)k * NG_ + orig_col(p)]);
  } else if (idx < N0 + N1){
    int j = idx - N0; int p = j >> 10, k = j & 1023;
    int oc = orig_col(p);
    float v = (k < 512) ? W1[(size_t)k * NG_ + oc] : U1[(size_t)(k - 512) * NG_ + oc];
    Bt1[j] = f2bf(v);
  } else if (idx < N0 + 2 * N1){
    int j = idx - N0 - N1; int p = j >> 10, k = j & 1023;
    int oc = orig_col(p);
    float v = (k < 512) ? W2[(size_t)k * NG_ + oc] : U2[(size_t)(k - 512) * NG_ + oc];
    Bt2[j] = f2bf(v);
  } else if (idx < N0 + 2 * N1 + NG_){
    int p = idx - N0 - 2 * N1;
    W0p[p] = W0[orig_col(p)];
  } else {
    int j = idx - N0 - 2 * N1 - NG_;
    int l = j >> 11, p = j & 2047;
    const float* bs = (l == 0) ? b0 : (l == 1) ? b1 : b2;
    biasp[j] = bs[orig_col(p)];
  }
}

// ---------------------------------------------------------------------------
// Fused GEMM (bf16 MFMA) + LSTM cell for one (layer, timestep), 128x128 tile.
// BK=32, DOUBLE-BUFFERED LDS with one barrier per K-iter:
//   for it: __syncthreads(); issue DMA for it+1 -> buf[(it+1)&1]; compute buf[it&1]
// The barrier's implicit vmcnt(0) drains loads issued one iteration ago —
// they've had a full compute phase to land, so the drain is cheap. The
// barrier also guarantees all threads finished reading the buffer we're
// about to overwrite.  (round-5 lesson: drain *exposure* is the bottleneck.)
// Slot rotation (slot j holds source chunk (j + (r>>1))&3) keeps the 16-lane
// ds_read_b128 groups at the free 2-way conflict level.
// 256 threads = 2x2 waves, each wave 4x4 frags of 16x16x32, 1 k-step/iter.
// ---------------------------------------------------------------------------
template<int LAYER>
__device__ __forceinline__ void do_task(
    const ushort_t* __restrict__ A0,   // phase-0 A (h_below / h_prev for L0)
    const ushort_t* __restrict__ A1,   // phase-1 A (h_prev), LAYER>0
    const ushort_t* __restrict__ Bt,   // (2048 x K) bf16, n-major permuted
    const float* __restrict__ biasp,   // permuted bias for this layer (2048)
    const float* __restrict__ W0p,     // permuted W0 row (L0 only)
    const float* __restrict__ x,       // (B,T) fp32 (L0 only)
    const int* __restrict__ mask,      // (B,T) int32
    float* __restrict__ cbuf,          // (B,U) fp32, in/out
    const ushort_t* __restrict__ hprev,// this layer's previous h (mask carry)
    ushort_t* __restrict__ hout,       // (B,U) bf16 out
    int t, int mt, int nt,
    ushort_t* tA, ushort_t* tB)        // each 2 x 128x32 elements (dbuf)
{
  constexpr int NPHASE = (LAYER == 0) ? 1 : 2;
  constexpr bool IS_L0 = (LAYER == 0);
  constexpr int K = NPHASE * 512;
  constexpr int NIT = NPHASE * 16;     // K-iters of 32

  const int tid  = threadIdx.x;
  const int wv   = tid >> 6;
  const int lane = tid & 63;
  const int qd   = lane >> 4;     // quad 0..3
  const int l16  = lane & 15;
  const int wave_m = wv >> 1;     // 0..1
  const int wave_n = wv & 1;      // 0..1
  const int m0 = mt * 128, n0 = nt * 128;

  // Staging identity: 512 16B-chunks per 128x32 tile, 2 per thread.
  // LDS dest chunk = i (wave-contiguous, DMA constraint); source 16B-col
  // sc = ((i&3) + (r>>1)) & 3  (row-pair rotation).
  int abase[2], bbase[2];
  #pragma unroll
  for (int g = 0; g < 2; ++g){
    int i = g * 256 + tid;
    int r = i >> 2;
    int sc = ((i & 3) + (r >> 1)) & 3;
    abase[g] = (m0 + r) * U_ + sc * 8;   // element offset; add k-offset per iter
    bbase[g] = (n0 + r) * K + sc * 8;
  }

  // Readback: frag row R wants global chunk qd -> slot (qd - (R>>1)) & 3.
  int aoff[4], boff[4];
  #pragma unroll
  for (int w = 0; w < 4; ++w){
    int Ra = wave_m * 64 + w * 16 + l16;
    int Rb = wave_n * 64 + w * 16 + l16;
    aoff[w] = Ra * 32 + ((qd - (Ra >> 1)) & 3) * 8;
    boff[w] = Rb * 32 + ((qd - (Rb >> 1)) & 3) * 8;
  }

  floatx4 acc[4][4];
  #pragma unroll
  for (int i = 0; i < 4; ++i)
    #pragma unroll
    for (int j = 0; j < 4; ++j) acc[i][j] = (floatx4){0.f, 0.f, 0.f, 0.f};

  // Stage iteration 0 into buffer 0.
  {
    const ushort_t* A = A0;
    #pragma unroll
    for (int g = 0; g < 2; ++g){
      int ibase = g * 256 + wv * 64;
      __builtin_amdgcn_global_load_lds(AS1(A + abase[g]), AS3(&tA[ibase * 8]), 16, 0, 0);
      __builtin_amdgcn_global_load_lds(AS1(Bt + bbase[g]), AS3(&tB[ibase * 8]), 16, 0, 0);
    }
  }

  #pragma unroll 2
  for (int it = 0; it < NIT; ++it){
    __syncthreads();   // drains prev-iter DMA (had a full compute phase to land)

    if (it + 1 < NIT){
      int nit = it + 1;
      int nk  = (nit & 15) * 32;                    // k-offset within 512
      const ushort_t* A = (NPHASE == 2 && nit >= 16) ? A1 : A0;
      int ak = nk;                                  // A k-offset (per-phase base)
      int bk = (NPHASE == 2 && nit >= 16) ? 512 + nk : nk;
      ushort_t* dA = tA + (nit & 1) * (128 * 32);
      ushort_t* dB = tB + (nit & 1) * (128 * 32);
      #pragma unroll
      for (int g = 0; g < 2; ++g){
        int ibase = g * 256 + wv * 64;
        __builtin_amdgcn_global_load_lds(AS1(A + abase[g] + ak), AS3(&dA[ibase * 8]), 16, 0, 0);
        __builtin_amdgcn_global_load_lds(AS1(Bt + bbase[g] + bk), AS3(&dB[ibase * 8]), 16, 0, 0);
      }
    }

    const ushort_t* sA = tA + (it & 1) * (128 * 32);
    const ushort_t* sB = tB + (it & 1) * (128 * 32);
    short8 af[4], bfr[4];
    #pragma unroll
    for (int wm = 0; wm < 4; ++wm) af[wm] = *(const short8*)&sA[aoff[wm]];
    #pragma unroll
    for (int wn = 0; wn < 4; ++wn) bfr[wn] = *(const short8*)&sB[boff[wn]];
    #pragma unroll
    for (int wm = 0; wm < 4; ++wm)
      #pragma unroll
      for (int wn = 0; wn < 4; ++wn)
        acc[wm][wn] = __builtin_amdgcn_mfma_f32_16x16x32_bf16(af[wm], bfr[wn], acc[wm][wn], 0, 0, 0);
  }

  // ---- epilogue: LSTM cell, fully in-register per lane ----
  const int u  = nt * 32 + wave_n * 16 + l16;
  const int pb = nt * 128 + wave_n * 64 + l16;
  const float bi = biasp[pb], bf_ = biasp[pb + 16], bg = biasp[pb + 32], bo = biasp[pb + 48];
  float wi = 0.f, wf = 0.f, wg = 0.f, wo = 0.f;
  if (IS_L0){ wi = W0p[pb]; wf = W0p[pb + 16]; wg = W0p[pb + 32]; wo = W0p[pb + 48]; }

  #pragma unroll
  for (int wm = 0; wm < 4; ++wm){
    #pragma unroll
    for (int reg = 0; reg < 4; ++reg){
      int b = m0 + wave_m * 64 + wm * 16 + qd * 4 + reg;
      float zi = acc[wm][0][reg] + bi;
      float zf = acc[wm][1][reg] + bf_;
      float zg = acc[wm][2][reg] + bg;
      float zo = acc[wm][3][reg] + bo;
      if (IS_L0){
        float xv = x[(size_t)b * T_ + t];
        zi += xv * wi; zf += xv * wf; zg += xv * wg; zo += xv * wo;
      }
      int mk = mask[(size_t)b * T_ + t];
      size_t su = (size_t)b * U_ + u;
      float c_old = cbuf[su];
      float i_ = sigm(zi), f_ = sigm(zf), g_ = tanh_fast(zg), o_ = sigm(zo);
      float c_new = f_ * c_old + i_ * g_;
      float h_new = o_ * tanh_fast(c_new);
      ushort_t hb = mk ? f2bf(h_new) : hprev[su];
      cbuf[su] = mk ? c_new : c_old;
      hout[su] = hb;
    }
  }
}

// ---------------------------------------------------------------------------
// One wavefront phase: L0(t=s), L1(t=s-1), L2(t=s-2) independent ->
// 768 blocks (3 tasks x 256 tiles) = 3 blocks/CU (12 waves/CU). task=lin>>8
// so blocks {lin, lin+256, lin+512} share a CU under round-robin dispatch:
// uniform per-CU load and shared mask/x cachelines.
// ---------------------------------------------------------------------------
__global__ __launch_bounds__(256, 3) void lstm_phase(
    const ushort_t* __restrict__ Bt0, const ushort_t* __restrict__ Bt1,
    const ushort_t* __restrict__ Bt2, const float* __restrict__ biasp,
    const float* __restrict__ W0p, const float* __restrict__ x,
    const int* __restrict__ mask,
    ushort_t* h00, ushort_t* h01, ushort_t* h10, ushort_t* h11,
    ushort_t* h20, ushort_t* h21,
    float* c0, float* c1, float* c2,
    int s)
{
  __shared__ __align__(16) ushort_t tA[2 * 128 * 32];
  __shared__ __align__(16) ushort_t tB[2 * 128 * 32];

  const int lin  = blockIdx.x;
  const int task = lin >> 8;        // 0..2
  const int tile = lin & 255;       // 0..255
  const int mt = tile >> 4, nt = tile & 15;

  ushort_t* h0[2] = {h00, h01};
  ushort_t* h1[2] = {h10, h11};
  ushort_t* h2[2] = {h20, h21};

  if (task == 0){
    if (s >= 100) return;
    int t = s, p = t & 1;
    do_task<0>(h0[p], nullptr, Bt0, biasp, W0p, x, mask,
               c0, h0[p], h0[p ^ 1], t, mt, nt, tA, tB);
  } else if (task == 1){
    if (s < 1 || s > 100) return;
    int t = s - 1, p = t & 1;
    do_task<1>(h0[p ^ 1], h1[p], Bt1, biasp + NG_, nullptr, x, mask,
               c1, h1[p], h1[p ^ 1], t, mt, nt, tA, tB);
  } else {
    if (s < 2) return;
    int t = s - 2, p = t & 1;
    do_task<2>(h1[p ^ 1], h2[p], Bt2, biasp + 2 * NG_, nullptr, x, mask,
               c2, h2[p], h2[p ^ 1], t, mt, nt, tA, tB);
  }
}

// ---------------------------------------------------------------------------
// Head: logits = h2 @ Wd + bd, softmax. One wave per batch row.
// ---------------------------------------------------------------------------
__global__ __launch_bounds__(256) void head_softmax(
    const ushort_t* __restrict__ h2, const float* __restrict__ Wd,
    const float* __restrict__ bd, float* __restrict__ out)
{
  int wv = threadIdx.x >> 6, lane = threadIdx.x & 63;
  int row = blockIdx.x * 4 + wv;
  const ushort_t* hr = h2 + (size_t)row * U_;

  float acc[C_];
  #pragma unroll
  for (int c = 0; c < C_; ++c) acc[c] = 0.f;

  short8 hv = *(const short8*)&hr[lane * 8];
  #pragma unroll
  for (int j = 0; j < 8; ++j){
    float hf = bf2f((ushort_t)hv[j]);
    int k = lane * 8 + j;
    #pragma unroll
    for (int c = 0; c < C_; ++c) acc[c] += hf * Wd[k * C_ + c];
  }
  #pragma unroll
  for (int c = 0; c < C_; ++c){
    float v = acc[c];
    #pragma unroll
    for (int off = 32; off > 0; off >>= 1) v += __shfl_xor(v, off);
    acc[c] = v + bd[c];
  }
  float mx = acc[0];
  #pragma unroll
  for (int c = 1; c < C_; ++c) mx = fmaxf(mx, acc[c]);
  float e[C_]; float s = 0.f;
  #pragma unroll
  for (int c = 0; c < C_; ++c){ e[c] = __expf(acc[c] - mx); s += e[c]; }
  float inv = 1.0f / s;
  if (lane == 0){
    #pragma unroll
    for (int c = 0; c < C_; ++c) out[(size_t)row * C_ + c] = e[c] * inv;
  }
}

// ---------------------------------------------------------------------------
extern "C" void kernel_launch(void* const* d_in, const int* in_sizes, int n_in,
                              void* d_out, int out_size, void* d_ws, size_t ws_size,
                              hipStream_t stream)
{
  const float* x  = (const float*)d_in[0];
  const int*  mask= (const int*)  d_in[1];
  const float* W0 = (const float*)d_in[2];
  const float* U0 = (const float*)d_in[3];
  const float* b0 = (const float*)d_in[4];
  const float* W1 = (const float*)d_in[5];
  const float* U1 = (const float*)d_in[6];
  const float* b1 = (const float*)d_in[7];
  const float* W2 = (const float*)d_in[8];
  const float* U2 = (const float*)d_in[9];
  const float* b2 = (const float*)d_in[10];
  const float* Wd = (const float*)d_in[11];
  const float* bd = (const float*)d_in[12];
  float* out = (float*)d_out;

  char* ws = (char*)d_ws;
  size_t off = 0;
  auto alloc = [&](size_t sz) -> char* {
    char* p = ws + off; off = (off + sz + 255) & ~(size_t)255; return p;
  };
  ushort_t* Bt0  = (ushort_t*)alloc((size_t)NG_ * 512 * 2);
  ushort_t* Bt1  = (ushort_t*)alloc((size_t)NG_ * 1024 * 2);
  ushort_t* Bt2  = (ushort_t*)alloc((size_t)NG_ * 1024 * 2);
  float*    W0p  = (float*)alloc((size_t)NG_ * 4);
  float*    biasp= (float*)alloc((size_t)3 * NG_ * 4);

  // State: h[3][2] (bf16) + c[3] (fp32), one contiguous memset region.
  const size_t hsz = (size_t)B_ * U_ * 2;
  const size_t csz = (size_t)B_ * U_ * 4;
  char* state = alloc(6 * hsz + 3 * csz);
  ushort_t* hb[3][2]; float* cb[3];
  {
    char* pp = state;
    for (int l = 0; l < 3; ++l)
      for (int par = 0; par < 2; ++par){ hb[l][par] = (ushort_t*)pp; pp += hsz; }
    for (int l = 0; l < 3; ++l){ cb[l] = (float*)pp; pp += csz; }
  }

  hipMemsetAsync(state, 0, 6 * hsz + 3 * csz, stream);

  const int total = NG_ * 512 + 2 * NG_ * 1024 + NG_ + 3 * NG_;
  convert_weights<<<(total + 255) / 256, 256, 0, stream>>>(
      W0, U0, b0, W1, U1, b1, W2, U2, b2, Bt0, Bt1, Bt2, W0p, biasp);

  for (int s = 0; s < 102; ++s){
    lstm_phase<<<768, 256, 0, stream>>>(
        Bt0, Bt1, Bt2, biasp, W0p, x, mask,
        hb[0][0], hb[0][1], hb[1][0], hb[1][1], hb[2][0], hb[2][1],
        cb[0], cb[1], cb[2], s);
  }

  // T=100: layer-2 final h (t=99) lands in parity-0 buffer.
  head_softmax<<<B_ / 4, 256, 0, stream>>>(hb[2][0], Wd, bd, out);
}